// Round 4
// baseline (449.038 us; speedup 1.0000x reference)
//
#include <hip/hip_runtime.h>
#include <math.h>

// VIN forward on MI355X — 256 WGs x 512 thr: each WG owns a 32-row half-image.
// Sizes: N=128, H=W=64, CH_I=2, CH_H=150, CH_Q=10, N_ACT=8, VInum=36.
//
// R14 -> R15 (structural): R14 counters: Occupancy 11% (128 WGs on 256 CUs =
// half chip idle), K-loop ~2.7us/iter vs 0.75us VALU floor; three rounds of
// in-loop micro-opts each bought ~10% -> the residual is the 8-wave lockstep
// + half-idle chip. VI dependency is 1 px/iter, so a half-image needs only
// ONE neighbor edge row per iteration. Split: 2 WGs per image (rows 0-31 /
// 32-63), 4 px/thread. Per-iter exchange of the 64-float edge row via
// workspace with agent-scope atomics (correct under XCD non-coherence);
// parity-double-buffered halo slots + monotonic flags (zeroed per launch by
// hipMemsetAsync, stream-ordered before the kernel -> graph-capture-safe).
// Causal chain peer-read(k-2) < peer-pub(k-1) < my-acq(k-1) < my-pub(k)
// makes slot reuse WAR-safe. All 256 WGs co-resident (59KB LDS, 8 waves,
// ~200 VGPR fit under any packing) -> spins always make progress.
// r needs no exchange: each WG computes r rows [s-1..s+32] locally from x.
// Per-element FP order unchanged from R14 -> absmax expected unchanged.

typedef float v2f __attribute__((ext_vector_type(2)));

static __device__ __forceinline__ v2f splat2(float s) { v2f r; r.x = s; r.y = s; return r; }
static __device__ __forceinline__ v2f pkfma(v2f w, float v, v2f a) {
#if __has_builtin(__builtin_elementwise_fma)
    return __builtin_elementwise_fma(w, splat2(v), a);
#else
    v2f r; r.x = fmaf(w.x, v, a.x); r.y = fmaf(w.y, v, a.y); return r;
#endif
}
static __device__ __forceinline__ v2f pkmax(v2f a, v2f b) {
#if __has_builtin(__builtin_elementwise_max)
    return __builtin_elementwise_max(a, b);
#else
    v2f r; r.x = fmaxf(a.x, b.x); r.y = fmaxf(a.y, b.y); return r;
#endif
}

#define XROW 69
#define VROW 67
#define XS_ROWS 38               // x rows s-3 .. s+34
#define RS_ROWS 34               // r rows s-1 .. s+32  (index ri = local+1)
#define VP_ROWS 34               // v rows s-1 .. s+32  (index = local+1)
#define VSTR (VP_ROWS * VROW)    // 2278 floats per v buffer

__global__ void
__attribute__((amdgpu_flat_work_group_size(512, 512)))
__attribute__((amdgpu_waves_per_eu(2, 2)))
vin_kernel(const float* __restrict__ x,
           const int* __restrict__ S1,
           const int* __restrict__ S2,
           const int* __restrict__ VInum,
           const float* __restrict__ w0,
           const float* __restrict__ b0,
           const float* __restrict__ w_r,
           const float* __restrict__ w_q,
           const float* __restrict__ w_sw,
           const float* __restrict__ w_sw2,
           const float* __restrict__ w_dense,
           float* __restrict__ out,
           void* __restrict__ ws) {
    const int g = blockIdx.x;
    const int t = threadIdx.x;
    // XCD-pair swizzle (perf-only): both halves of an image on one XCD.
    const int xcd  = g & 7;
    const int slot = g >> 3;           // 0..31
    const int b    = xcd * 16 + (slot >> 1);   // image 0..127
    const int h    = slot & 1;                 // half: 0 = rows 0-31, 1 = 32-63
    const int s    = h << 5;                   // strip start row

    int*   F    = (int*)ws;                    // 256 flags (memset to 0 pre-launch)
    float* Hbuf = (float*)ws + 256;            // halo[imghalf][parity][64]
    const int selfIdx = b * 2 + h;
    const int peerIdx = b * 2 + (h ^ 1);

    __shared__ float xs0[XS_ROWS * XROW];  // x ch0, 2-col zero halo, strip+3 rows
    __shared__ float xs1[XS_ROWS * XROW];  // x ch1
    __shared__ float rs[RS_ROWS * VROW];   // r rows s-1..s+32, 1-col zero halo
    __shared__ float vpool[2 * VSTR];      // v double buffer, rows s-1..s+32
    __shared__ float wtA[1620];            // P chunk partials: 162 entries x 10
    __shared__ float Pp[450];              // P[d][e5x5][ci], zero-init
    __shared__ float Bt[90];               // bias chunk partials
    __shared__ float Bv[9];                // B[d] = w_r[d].b0
    __shared__ float W5c[459];             // 9 classes x (50 weights + bias)
    __shared__ v2f   swv2[45];             // w_sw v-part action-pairs: [d][ap]
    __shared__ float qsel[10];

    // ---- zero LDS ----
    for (int i = t; i < XS_ROWS * XROW; i += 512) { xs0[i] = 0.f; xs1[i] = 0.f; }
    for (int i = t; i < RS_ROWS * VROW; i += 512) rs[i] = 0.f;
    for (int i = t; i < 2 * VSTR; i += 512) vpool[i] = 0.f;
    if (t < 450) Pp[t] = 0.f;
    if (t < 45) {
        int d = t / 5, ap = t - d * 5;
        v2f w; w.x = w_sw[d * 20 + 10 + 2 * ap]; w.y = w_sw[d * 20 + 10 + 2 * ap + 1];
        swv2[t] = w;
    }
    __syncthreads();

    // ---- stage x rows s-3..s+34 (clipped) ----
    for (int i = t; i < XS_ROWS * 32; i += 512) {
        int xl = i >> 5, grp = i & 31;
        int gx = s - 3 + xl;
        if (gx < 0 || gx > 63) continue;
        float4 v4 = *(const float4*)(x + ((size_t)(b * 64 + gx) * 64 + grp * 2) * 2);
        int px = grp * 2;
        xs0[xl * XROW + px + 2] = v4.x; xs1[xl * XROW + px + 2] = v4.y;
        xs0[xl * XROW + px + 3] = v4.z; xs1[xl * XROW + px + 3] = v4.w;
    }
    // ---- round A: P chunk partials (1620) + bias chunks (90) ----
    for (int idx = t; idx < 1620; idx += 512) {
        int entry = idx / 10, ch = idx - entry * 10;
        int d = entry / 18, rem = entry % 18;
        int uu = rem >> 1, ci = rem & 1;
        int c0 = ch * 15;
        const float* wr = w_r + d * 150;
        const float* wp = w0 + (uu * 2 + ci) * 150;
        float ssum = 0.f;
        for (int c = c0; c < c0 + 15; ++c) ssum += wr[c] * wp[c];
        wtA[idx] = ssum;
    }
    if (t < 90) {
        int d = t / 10, ch = t - d * 10, c0 = ch * 15;
        float ssum = 0.f;
        for (int c = c0; c < c0 + 15; ++c) ssum += w_r[d * 150 + c] * b0[c];
        Bt[t] = ssum;
    }
    __syncthreads();
    // ---- round B: reduce P entries (162) and B (9) ----
    if (t < 162) {
        float ssum = 0.f;
        #pragma unroll
        for (int i = 0; i < 10; ++i) ssum += wtA[t * 10 + i];
        int d = t / 18, rem = t % 18;
        int uu = rem >> 1, ci = rem & 1;
        int dy = d / 3 - 1, dx = d % 3 - 1;
        int uy = uu / 3 - 1, ux = uu % 3 - 1;
        int eidx = (dy + uy + 2) * 5 + (dx + ux + 2);
        Pp[d * 50 + eidx * 2 + ci] = ssum;
    } else if (t >= 256 && t < 265) {
        int d = t - 256;
        float ssum = 0.f;
        #pragma unroll
        for (int i = 0; i < 10; ++i) ssum += Bt[d * 10 + i];
        Bv[d] = ssum;
    }
    __syncthreads();
    // ---- round C: class subset-sums W5c[9][51] ----
    if (t < 459) {
        int cls = t / 51, j = t - cls * 51;
        int cy = cls / 3, cx = cls % 3;
        float ssum = 0.f;
        #pragma unroll
        for (int d = 0; d < 9; ++d) {
            int dy = d / 3 - 1, dx = d % 3 - 1;
            bool ok = (cy == 0 || (cy == 1 ? dy >= 0 : dy <= 0)) &&
                      (cx == 0 || (cx == 1 ? dx >= 0 : dx <= 0));
            if (ok) ssum += (j < 50) ? Pp[d * 50 + j] : Bv[d];
        }
        W5c[t] = ssum;
    }
    __syncthreads();

    // ---- r for rows s-1..s+32 (34 rows) via class-weighted 5x5 stencil ----
    for (int i = t; i < RS_ROWS * 64; i += 512) {
        int ri = i >> 6;             // rs row index 0..33, global gy = s-1+ri
        int c  = i & 63;
        int gy = s + ri - 1;
        if (gy < 0 || gy > 63) continue;   // image halo rows stay zero
        int cy = (gy == 0) ? 1 : (gy == 63) ? 2 : 0;
        int cx = (c == 0) ? 1 : (c == 63) ? 2 : 0;
        const float* Wp = &W5c[(cy * 3 + cx) * 51];
        float acc = Wp[50];
        #pragma unroll
        for (int e = 0; e < 25; ++e) {
            int xi = (ri + e / 5) * XROW + (c + e % 5);
            acc = fmaf(xs0[xi], Wp[e * 2], acc);
            acc = fmaf(xs1[xi], Wp[e * 2 + 1], acc);
        }
        rs[ri * VROW + (c + 1)] = acc;
    }
    __syncthreads();

    const int K = VInum[0];
    const int rl = t >> 4;           // local row 0..31
    const int cb = (t & 15) << 2;    // 0,4,...,60 (4 px per thread)
    const int edgeRl  = (h == 0) ? 31 : 0;   // row published to peer
    const int haloRow = (h == 0) ? 33 : 0;   // vpool row receiving peer halo
    const bool isEdge = (rl == edgeRl);

    // ---- Rsw precompute (packed action-pairs) + first step (w_q) ----
    v2f Rsw2[4][5];
    float vprev[4];
    {
        float rwin[3][6];
        #pragma unroll
        for (int i = 0; i < 3; ++i) {
            const float* rp = &rs[(rl + i) * VROW + cb];
            #pragma unroll
            for (int j = 0; j < 6; ++j) rwin[i][j] = rp[j];
        }
        float vmax[4];
        #pragma unroll
        for (int a = 0; a < 10; ++a) {
            #pragma unroll
            for (int p = 0; p < 4; ++p) {
                float accR = 0.f, accQ = 0.f;
                #pragma unroll
                for (int d = 0; d < 9; ++d) {
                    float rv = rwin[d / 3][p + d % 3];
                    accR = fmaf(w_sw[d * 20 + a], rv, accR);
                    accQ = fmaf(w_q[d * 20 + a],  rv, accQ);
                }
                if (a & 1) Rsw2[p][a >> 1].y = accR; else Rsw2[p][a >> 1].x = accR;
                vmax[p] = (a == 0) ? accQ : fmaxf(vmax[p], accQ);
            }
        }
        // publish v^1 edge row (from registers) then write LDS
        if (isEdge) {
            float* dst = Hbuf + (selfIdx * 2 + 1) * 64 + cb;
            #pragma unroll
            for (int p = 0; p < 4; ++p)
                __hip_atomic_store(&dst[p], vmax[p], __ATOMIC_RELAXED, __HIP_MEMORY_SCOPE_AGENT);
            if ((t & 15) == 0)
                __hip_atomic_store(&F[selfIdx], 1, __ATOMIC_RELEASE, __HIP_MEMORY_SCOPE_AGENT);
        }
        #pragma unroll
        for (int p = 0; p < 4; ++p) {
            vpool[0 * VSTR + (rl + 1) * VROW + (cb + p + 1)] = vmax[p];
            vprev[p] = vmax[p];
        }
    }
    // acquire v^1 halo row from peer
    if (t < 64) {
        while (__hip_atomic_load(&F[peerIdx], __ATOMIC_ACQUIRE, __HIP_MEMORY_SCOPE_AGENT) < 1)
            __builtin_amdgcn_s_sleep(2);
        float hv = __hip_atomic_load(&Hbuf[(peerIdx * 2 + 1) * 64 + t],
                                     __ATOMIC_RELAXED, __HIP_MEMORY_SCOPE_AGENT);
        vpool[0 * VSTR + haloRow * VROW + (t + 1)] = hv;
    }
    __syncthreads();

    // ---- hoist loop-invariant w_sw v-part weights into registers ----
    v2f wreg[45];
    #pragma unroll
    for (int i = 0; i < 45; ++i) wreg[i] = swv2[i];

    // ---- shared-weight VI steps k = 2..K (producing v^k) ----
    int cur = 0;
    for (int k = 2; k <= K; ++k) {
        const float* vb = &vpool[cur * VSTR + rl * VROW + cb];
        float v0[6], v2[6];
        #pragma unroll
        for (int j = 0; j < 6; ++j) v0[j] = vb[j];
        #pragma unroll
        for (int j = 0; j < 6; ++j) v2[j] = vb[2 * VROW + j];
        float eL = vb[VROW], eR = vb[VROW + 5];
        float v1[6];
        v1[0] = eL; v1[5] = eR;
        #pragma unroll
        for (int j = 0; j < 4; ++j) v1[j + 1] = vprev[j];

        int nxt = cur ^ 1;
        v2f vmax2[4];
        #pragma unroll
        for (int ap = 0; ap < 5; ++ap) {
            v2f acc[4];
            #pragma unroll
            for (int d = 0; d < 9; ++d) {
                v2f w2 = wreg[d * 5 + ap];
                const float* vr = (d < 3) ? v0 : (d < 6) ? v1 : v2;
                #pragma unroll
                for (int p = 0; p < 4; ++p) {
                    float vv = vr[p + d % 3];
                    acc[p] = (d == 0) ? pkfma(w2, vv, Rsw2[p][ap])
                                      : pkfma(w2, vv, acc[p]);
                }
            }
            #pragma unroll
            for (int p = 0; p < 4; ++p)
                vmax2[p] = (ap == 0) ? acc[p] : pkmax(vmax2[p], acc[p]);
        }
        float vnew[4];
        #pragma unroll
        for (int p = 0; p < 4; ++p) vnew[p] = fmaxf(vmax2[p].x, vmax2[p].y);

        // publish edge row of v^k (regs -> IC) before LDS writes
        if (isEdge) {
            float* dst = Hbuf + (selfIdx * 2 + (k & 1)) * 64 + cb;
            #pragma unroll
            for (int p = 0; p < 4; ++p)
                __hip_atomic_store(&dst[p], vnew[p], __ATOMIC_RELAXED, __HIP_MEMORY_SCOPE_AGENT);
            if ((t & 15) == 0)
                __hip_atomic_store(&F[selfIdx], k, __ATOMIC_RELEASE, __HIP_MEMORY_SCOPE_AGENT);
        }
        float* vw = &vpool[nxt * VSTR + (rl + 1) * VROW + cb + 1];
        #pragma unroll
        for (int p = 0; p < 4; ++p) { vw[p] = vnew[p]; vprev[p] = vnew[p]; }

        // acquire peer edge row of v^k into the halo slot of the new buffer
        if (t < 64) {
            while (__hip_atomic_load(&F[peerIdx], __ATOMIC_ACQUIRE, __HIP_MEMORY_SCOPE_AGENT) < k)
                __builtin_amdgcn_s_sleep(2);
            float hv = __hip_atomic_load(&Hbuf[(peerIdx * 2 + (k & 1)) * 64 + t],
                                         __ATOMIC_RELAXED, __HIP_MEMORY_SCOPE_AGENT);
            vpool[nxt * VSTR + haloRow * VROW + (t + 1)] = hv;
        }
        __syncthreads();
        cur = nxt;
    }

    // ---- final step with w_sw2: q -> global, gather (S1,S2) ----
    const int s1 = S1[b], s2 = S2[b];
    const int gy = s + rl;
    {
        float rwin[3][6], vwin[3][6];
        #pragma unroll
        for (int i = 0; i < 3; ++i) {
            const float* rp = &rs[(rl + i) * VROW + cb];
            #pragma unroll
            for (int j = 0; j < 6; ++j) rwin[i][j] = rp[j];
        }
        const float* vb = &vpool[cur * VSTR + rl * VROW + cb];
        #pragma unroll
        for (int j = 0; j < 6; ++j) vwin[0][j] = vb[j];
        #pragma unroll
        for (int j = 0; j < 6; ++j) vwin[2][j] = vb[2 * VROW + j];
        vwin[1][0] = vb[VROW]; vwin[1][5] = vb[VROW + 5];
        #pragma unroll
        for (int j = 0; j < 4; ++j) vwin[1][j + 1] = vprev[j];

        float qv[4][10];
        #pragma unroll
        for (int a = 0; a < 10; ++a) {
            #pragma unroll
            for (int p = 0; p < 4; ++p) {
                float acc = 0.f;
                #pragma unroll
                for (int d = 0; d < 9; ++d) {
                    acc = fmaf(w_sw2[d * 20 + a],      rwin[d / 3][p + d % 3], acc);
                    acc = fmaf(w_sw2[d * 20 + 10 + a], vwin[d / 3][p + d % 3], acc);
                }
                qv[p][a] = acc;
            }
        }
        // store q: 40 contiguous floats (4 px x 10 actions), 16B-aligned
        {
            float4* qp4 = (float4*)(out + 2048 + ((size_t)((b * 64 + gy) * 64 + cb)) * 10);
            #pragma unroll
            for (int gq = 0; gq < 10; ++gq)
                qp4[gq] = make_float4(qv[(gq * 4) / 10][(gq * 4) % 10],
                                      qv[(gq * 4 + 1) / 10][(gq * 4 + 1) % 10],
                                      qv[(gq * 4 + 2) / 10][(gq * 4 + 2) % 10],
                                      qv[(gq * 4 + 3) / 10][(gq * 4 + 3) % 10]);
        }
        if ((s1 >> 5) == h && rl == (s1 & 31)) {
            #pragma unroll
            for (int p = 0; p < 4; ++p)
                if (s2 == cb + p) {
                    #pragma unroll
                    for (int a = 0; a < 10; ++a) qsel[a] = qv[p][a];
                }
        }
    }
    __syncthreads();

    // ---- dense + softmax + q_out (only the half owning row S1) ----
    if ((s1 >> 5) == h) {
        if (t == 0) {
            float logits[8];
            float m = -1e30f;
            #pragma unroll
            for (int j = 0; j < 8; ++j) {
                float ssum = 0.f;
                #pragma unroll
                for (int a = 0; a < 10; ++a) ssum += qsel[a] * w_dense[a * 8 + j];
                logits[j] = ssum;
                m = fmaxf(m, ssum);
            }
            float sum = 0.f;
            float e[8];
            #pragma unroll
            for (int j = 0; j < 8; ++j) { e[j] = expf(logits[j] - m); sum += e[j]; }
            float inv = 1.f / sum;
            #pragma unroll
            for (int j = 0; j < 8; ++j) {
                out[b * 8 + j] = logits[j];
                out[1024 + b * 8 + j] = e[j] * inv;
            }
        }
        if (t < 10) out[5244928 + b * 10 + t] = qsel[t];
    }
}

extern "C" void kernel_launch(void* const* d_in, const int* in_sizes, int n_in,
                              void* d_out, int out_size, void* d_ws, size_t ws_size,
                              hipStream_t stream) {
    const float* x      = (const float*)d_in[0];
    const int*   S1     = (const int*)d_in[1];
    const int*   S2     = (const int*)d_in[2];
    const int*   VInum  = (const int*)d_in[3];
    const float* w0     = (const float*)d_in[4];
    const float* b0     = (const float*)d_in[5];
    const float* w_r    = (const float*)d_in[6];
    const float* w_q    = (const float*)d_in[7];
    const float* w_sw   = (const float*)d_in[8];
    const float* w_sw2  = (const float*)d_in[9];
    const float* w_dense= (const float*)d_in[10];
    float* out = (float*)d_out;

    // zero the 256 exchange flags (stream-ordered before the kernel;
    // hipMemsetAsync is graph-capture-safe — the harness itself uses it)
    hipMemsetAsync(d_ws, 0, 256 * sizeof(int), stream);
    vin_kernel<<<256, 512, 0, stream>>>(x, S1, S2, VInum, w0, b0, w_r, w_q,
                                        w_sw, w_sw2, w_dense, out, d_ws);
}

// Round 5
// 176.663 us; speedup vs baseline: 2.5418x; 2.5418x over previous
//
#include <hip/hip_runtime.h>
#include <math.h>

// VIN forward on MI355X — single fused kernel, 128 WGs x 1024 thr (16 waves,
// 4/SIMD), 4 px/thread. Sizes: N=128, H=W=64, CH_I=2, CH_H=150, CH_Q=10.
//
// R15 -> R16: R15 (cross-WG exchange) = 3.5x REGRESSION (11us/iter exchange
// latency, VALUBusy 7.8%) -> reverted to R14 structure. R14 accounting:
// VALU-busy 28us, LDS-busy ~31us, wall 111us -> latency-bound at 2 waves/
// SIMD (pipes <30% busy; each removed LDS op bought ~24cyc critical path).
// Bank-conflict counter tracks benign 2-way aliasing (pattern computes to
// exactly 2 lanes/bank = free per m136) -> red herring, ignore it.
// Fixes (bit-identical math, same per-px FP order):
//  (1) 1024 threads / 4 px/thread: 2x waves per SIMD to hide LDS latency
//      and barrier skew. Hard VGPR cap 128 for 16 waves/CU.
//  (2) K-loop weights read directly from global (uniform literal index ->
//      loop-invariant s_load, SGPR/K$-resident, scalar pipe) instead of a
//      90-VGPR wreg array — frees the VGPR budget for (1).
//  (3) vpool/rs stride 67 -> 68 with 2-float left pad: every 6-wide window
//      is covered by 16B-aligned chunks -> K-loop LDS = 4 ds_read_b128 +
//      2 b32 + 2 ds_write_b64 (8 ops/thread/iter vs 30 scalar).

typedef float v2f __attribute__((ext_vector_type(2)));

static __device__ __forceinline__ v2f splat2(float s) { v2f r; r.x = s; r.y = s; return r; }
static __device__ __forceinline__ v2f pkfma(v2f w, float v, v2f a) {
#if __has_builtin(__builtin_elementwise_fma)
    return __builtin_elementwise_fma(w, splat2(v), a);
#else
    v2f r; r.x = fmaf(w.x, v, a.x); r.y = fmaf(w.y, v, a.y); return r;
#endif
}
static __device__ __forceinline__ v2f pkmax(v2f a, v2f b) {
#if __has_builtin(__builtin_elementwise_max)
    return __builtin_elementwise_max(a, b);
#else
    v2f r; r.x = fmaxf(a.x, b.x); r.y = fmaxf(a.y, b.y); return r;
#endif
}

#define XROW 69
#define RROW 68                  // rs row stride; addr = row*68 + col + 2
#define VROW2 68                 // vpool row stride; addr = row*68 + col + 2
#define VSTR2 (66 * VROW2)       // 4488 floats per v buffer

__global__ void
__attribute__((amdgpu_flat_work_group_size(1024, 1024)))
__attribute__((amdgpu_waves_per_eu(4, 4)))
vin_kernel(const float* __restrict__ x,
           const int* __restrict__ S1,
           const int* __restrict__ S2,
           const int* __restrict__ VInum,
           const float* __restrict__ w0,
           const float* __restrict__ b0,
           const float* __restrict__ w_r,
           const float* __restrict__ w_q,
           const float* __restrict__ w_sw,
           const float* __restrict__ w_sw2,
           const float* __restrict__ w_dense,
           float* __restrict__ out) {
    const int b = blockIdx.x;
    const int t = threadIdx.x;

    __shared__ float xs0[68 * XROW];     // x ch0, [y+2][x+2], 2-halo of zeros
    __shared__ float xs1[68 * XROW];     // x ch1
    __shared__ float rs[66 * RROW];      // r, pad-2 layout, zero halos
    __shared__ float vpool[2 * VSTR2];   // v double buffer, pad-2 layout
    __shared__ float wtA[1620];          // P chunk partials: 162 entries x 10
    __shared__ float Pp[450];            // P[d][e5x5][ci], zero-init
    __shared__ float Bt[90];             // bias chunk partials
    __shared__ float Bv[9];              // B[d] = w_r[d].b0
    __shared__ float W5c[459];           // 9 classes x (50 weights + bias)
    __shared__ float qsel[10];

    // ---- zero LDS (halos must be 0; Pp must be 0 for invalid combos) ----
    for (int i = t; i < 68 * XROW; i += 1024) { xs0[i] = 0.f; xs1[i] = 0.f; }
    for (int i = t; i < 66 * RROW; i += 1024) rs[i] = 0.f;
    for (int i = t; i < 2 * VSTR2; i += 1024) vpool[i] = 0.f;
    if (t < 450) Pp[t] = 0.f;
    __syncthreads();

    const int row = t >> 4;          // 0..63
    const int cb  = (t & 15) << 2;   // 0,4,...,60  (4 px per thread)

    // ---- stage x (8 contiguous floats = 2x float4 per thread) ----
    {
        const float* xb = x + (size_t)b * 64 * 64 * 2;
        const float4* xp = (const float4*)(xb + (row * 64 + cb) * 2);
        #pragma unroll
        for (int g = 0; g < 2; ++g) {
            float4 v4 = xp[g];
            int px = cb + g * 2;
            xs0[(row + 2) * XROW + px + 2] = v4.x;
            xs1[(row + 2) * XROW + px + 2] = v4.y;
            xs0[(row + 2) * XROW + px + 3] = v4.z;
            xs1[(row + 2) * XROW + px + 3] = v4.w;
        }
    }
    // ---- round A: P chunk partials (1620 items) + bias chunks (90) ----
    for (int idx = t; idx < 1620; idx += 1024) {
        int entry = idx / 10, ch = idx - entry * 10;
        int d = entry / 18, rem = entry % 18;
        int uu = rem >> 1, ci = rem & 1;
        int c0 = ch * 15;
        const float* wr = w_r + d * 150;
        const float* wp = w0 + (uu * 2 + ci) * 150;
        float s = 0.f;
        for (int c = c0; c < c0 + 15; ++c) s += wr[c] * wp[c];
        wtA[idx] = s;
    }
    if (t < 90) {
        int d = t / 10, ch = t - d * 10, c0 = ch * 15;
        float s = 0.f;
        for (int c = c0; c < c0 + 15; ++c) s += w_r[d * 150 + c] * b0[c];
        Bt[t] = s;
    }
    __syncthreads();
    // ---- round B: reduce P entries (162) and B (9) ----
    if (t < 162) {
        float s = 0.f;
        #pragma unroll
        for (int i = 0; i < 10; ++i) s += wtA[t * 10 + i];
        int d = t / 18, rem = t % 18;
        int uu = rem >> 1, ci = rem & 1;
        int dy = d / 3 - 1, dx = d % 3 - 1;
        int uy = uu / 3 - 1, ux = uu % 3 - 1;
        int eidx = (dy + uy + 2) * 5 + (dx + ux + 2);
        Pp[d * 50 + eidx * 2 + ci] = s;
    } else if (t >= 256 && t < 265) {
        int d = t - 256;
        float s = 0.f;
        #pragma unroll
        for (int i = 0; i < 10; ++i) s += Bt[d * 10 + i];
        Bv[d] = s;
    }
    __syncthreads();
    // ---- round C: class subset-sums W5c[9][51] ----
    if (t < 459) {
        int cls = t / 51, j = t - cls * 51;
        int cy = cls / 3, cx = cls % 3;
        float s = 0.f;
        #pragma unroll
        for (int d = 0; d < 9; ++d) {
            int dy = d / 3 - 1, dx = d % 3 - 1;
            bool ok = (cy == 0 || (cy == 1 ? dy >= 0 : dy <= 0)) &&
                      (cx == 0 || (cx == 1 ? dx >= 0 : dx <= 0));
            if (ok) s += (j < 50) ? Pp[d * 50 + j] : Bv[d];
        }
        W5c[t] = s;
    }
    __syncthreads();

    // ---- r everywhere via class-weighted 5x5 stencil (4 px/thread) ----
    {
        int cy = (row == 0) ? 1 : (row == 63) ? 2 : 0;
        #pragma unroll
        for (int p = 0; p < 4; ++p) {
            int xx = cb + p;
            int cx = (xx == 0) ? 1 : (xx == 63) ? 2 : 0;
            const float* Wp = &W5c[(cy * 3 + cx) * 51];
            float acc = Wp[50];
            #pragma unroll
            for (int e = 0; e < 25; ++e) {
                int xi = (row + e / 5) * XROW + (xx + e % 5);
                acc = fmaf(xs0[xi], Wp[e * 2], acc);
                acc = fmaf(xs1[xi], Wp[e * 2 + 1], acc);
            }
            rs[(row + 1) * RROW + xx + 2] = acc;
        }
    }
    __syncthreads();

    const int K = VInum[0];

    // ---- Rsw precompute (packed action-pairs) + first step (w_q) ----
    v2f Rsw2[4][5];
    float vprev[4];
    {
        float rwin[3][6];
        #pragma unroll
        for (int i = 0; i < 3; ++i) {
            const float4* rp = (const float4*)&rs[(row + i) * RROW + cb];
            float4 cA = rp[0], cB = rp[1];
            rwin[i][0] = cA.y; rwin[i][1] = cA.z; rwin[i][2] = cA.w;
            rwin[i][3] = cB.x; rwin[i][4] = cB.y; rwin[i][5] = cB.z;
        }
        float vmax[4];
        #pragma unroll
        for (int a = 0; a < 10; ++a) {
            #pragma unroll
            for (int p = 0; p < 4; ++p) {
                float accR = 0.f, accQ = 0.f;
                #pragma unroll
                for (int d = 0; d < 9; ++d) {
                    float rv = rwin[d / 3][p + d % 3];
                    accR = fmaf(w_sw[d * 20 + a], rv, accR);
                    accQ = fmaf(w_q[d * 20 + a],  rv, accQ);
                }
                if (a & 1) Rsw2[p][a >> 1].y = accR; else Rsw2[p][a >> 1].x = accR;
                vmax[p] = (a == 0) ? accQ : fmaxf(vmax[p], accQ);
            }
        }
        #pragma unroll
        for (int p = 0; p < 4; ++p) {
            vpool[0 * VSTR2 + (row + 1) * VROW2 + cb + p + 2] = vmax[p];
            vprev[p] = vmax[p];
        }
    }
    __syncthreads();

    // ---- K-1 shared-weight VI steps ----
    // LDS per iter: 4 ds_read_b128 + 2 b32 + 2 ds_write_b64. Weights are
    // uniform global reads (loop-invariant s_load -> SGPR/K$).
    int cur = 0;
    for (int it = 0; it < K - 1; ++it) {
        const float* vb = &vpool[cur * VSTR2 + row * VROW2 + cb];
        const float4* r0p = (const float4*)vb;
        const float4* r2p = (const float4*)(vb + 2 * VROW2);
        float4 a0 = r0p[0], b0v = r0p[1];
        float4 a2 = r2p[0], b2v = r2p[1];
        float eL = vb[VROW2 + 1];
        float eR = vb[VROW2 + 6];
        float v0[6], v1[6], v2a[6];
        v0[0] = a0.y; v0[1] = a0.z; v0[2] = a0.w;
        v0[3] = b0v.x; v0[4] = b0v.y; v0[5] = b0v.z;
        v2a[0] = a2.y; v2a[1] = a2.z; v2a[2] = a2.w;
        v2a[3] = b2v.x; v2a[4] = b2v.y; v2a[5] = b2v.z;
        v1[0] = eL; v1[5] = eR;
        #pragma unroll
        for (int j = 0; j < 4; ++j) v1[j + 1] = vprev[j];

        int nxt = cur ^ 1;
        v2f vmax2[4];
        #pragma unroll
        for (int ap = 0; ap < 5; ++ap) {
            v2f acc[4];
            #pragma unroll
            for (int d = 0; d < 9; ++d) {
                v2f w2;
                w2.x = w_sw[d * 20 + 10 + 2 * ap];       // uniform -> s_load,
                w2.y = w_sw[d * 20 + 10 + 2 * ap + 1];   // loop-invariant
                const float* vr = (d < 3) ? v0 : (d < 6) ? v1 : v2a;
                #pragma unroll
                for (int p = 0; p < 4; ++p) {
                    float vv = vr[p + d % 3];
                    acc[p] = (d == 0) ? pkfma(w2, vv, Rsw2[p][ap])
                                      : pkfma(w2, vv, acc[p]);
                }
            }
            #pragma unroll
            for (int p = 0; p < 4; ++p)
                vmax2[p] = (ap == 0) ? acc[p] : pkmax(vmax2[p], acc[p]);
        }
        float vnew[4];
        #pragma unroll
        for (int p = 0; p < 4; ++p) vnew[p] = fmaxf(vmax2[p].x, vmax2[p].y);

        float* vw = &vpool[nxt * VSTR2 + (row + 1) * VROW2 + cb + 2];
        *(float2*)&vw[0] = make_float2(vnew[0], vnew[1]);   // ds_write_b64
        *(float2*)&vw[2] = make_float2(vnew[2], vnew[3]);   // ds_write_b64
        #pragma unroll
        for (int p = 0; p < 4; ++p) vprev[p] = vnew[p];

        cur = nxt;
        __syncthreads();
    }

    // ---- final step with w_sw2: q -> global, gather (S1,S2) ----
    const int s1 = S1[b], s2 = S2[b];
    {
        float rwin[3][6], vwin[3][6];
        #pragma unroll
        for (int i = 0; i < 3; ++i) {
            const float4* rp = (const float4*)&rs[(row + i) * RROW + cb];
            float4 cA = rp[0], cB = rp[1];
            rwin[i][0] = cA.y; rwin[i][1] = cA.z; rwin[i][2] = cA.w;
            rwin[i][3] = cB.x; rwin[i][4] = cB.y; rwin[i][5] = cB.z;
        }
        const float* vb = &vpool[cur * VSTR2 + row * VROW2 + cb];
        {
            const float4* r0p = (const float4*)vb;
            const float4* r2p = (const float4*)(vb + 2 * VROW2);
            float4 a0 = r0p[0], b0v = r0p[1];
            float4 a2 = r2p[0], b2v = r2p[1];
            vwin[0][0] = a0.y; vwin[0][1] = a0.z; vwin[0][2] = a0.w;
            vwin[0][3] = b0v.x; vwin[0][4] = b0v.y; vwin[0][5] = b0v.z;
            vwin[2][0] = a2.y; vwin[2][1] = a2.z; vwin[2][2] = a2.w;
            vwin[2][3] = b2v.x; vwin[2][4] = b2v.y; vwin[2][5] = b2v.z;
            vwin[1][0] = vb[VROW2 + 1]; vwin[1][5] = vb[VROW2 + 6];
            #pragma unroll
            for (int j = 0; j < 4; ++j) vwin[1][j + 1] = vprev[j];
        }
        float qv[4][10];
        #pragma unroll
        for (int a = 0; a < 10; ++a) {
            #pragma unroll
            for (int p = 0; p < 4; ++p) {
                float acc = 0.f;
                #pragma unroll
                for (int d = 0; d < 9; ++d) {
                    acc = fmaf(w_sw2[d * 20 + a],      rwin[d / 3][p + d % 3], acc);
                    acc = fmaf(w_sw2[d * 20 + 10 + a], vwin[d / 3][p + d % 3], acc);
                }
                qv[p][a] = acc;
            }
        }
        // store q: 40 contiguous floats (4 px x 10 actions), 16B-aligned
        {
            float4* qp4 = (float4*)(out + 2048 + ((size_t)((b * 64 + row) * 64 + cb)) * 10);
            #pragma unroll
            for (int g = 0; g < 10; ++g)
                qp4[g] = make_float4(qv[(g * 4) / 10][(g * 4) % 10],
                                     qv[(g * 4 + 1) / 10][(g * 4 + 1) % 10],
                                     qv[(g * 4 + 2) / 10][(g * 4 + 2) % 10],
                                     qv[(g * 4 + 3) / 10][(g * 4 + 3) % 10]);
        }
        if (row == s1) {
            #pragma unroll
            for (int p = 0; p < 4; ++p)
                if (s2 == cb + p) {
                    #pragma unroll
                    for (int a = 0; a < 10; ++a) qsel[a] = qv[p][a];
                }
        }
    }
    __syncthreads();

    // ---- dense + softmax (thread 0), q_out (threads 0..9) ----
    if (t == 0) {
        float logits[8];
        float m = -1e30f;
        #pragma unroll
        for (int j = 0; j < 8; ++j) {
            float s = 0.f;
            #pragma unroll
            for (int a = 0; a < 10; ++a) s += qsel[a] * w_dense[a * 8 + j];
            logits[j] = s;
            m = fmaxf(m, s);
        }
        float sum = 0.f;
        float e[8];
        #pragma unroll
        for (int j = 0; j < 8; ++j) { e[j] = expf(logits[j] - m); sum += e[j]; }
        float inv = 1.f / sum;
        #pragma unroll
        for (int j = 0; j < 8; ++j) {
            out[b * 8 + j] = logits[j];
            out[1024 + b * 8 + j] = e[j] * inv;
        }
    }
    if (t < 10) out[5244928 + b * 10 + t] = qsel[t];
}

extern "C" void kernel_launch(void* const* d_in, const int* in_sizes, int n_in,
                              void* d_out, int out_size, void* d_ws, size_t ws_size,
                              hipStream_t stream) {
    const float* x      = (const float*)d_in[0];
    const int*   S1     = (const int*)d_in[1];
    const int*   S2     = (const int*)d_in[2];
    const int*   VInum  = (const int*)d_in[3];
    const float* w0     = (const float*)d_in[4];
    const float* b0     = (const float*)d_in[5];
    const float* w_r    = (const float*)d_in[6];
    const float* w_q    = (const float*)d_in[7];
    const float* w_sw   = (const float*)d_in[8];
    const float* w_sw2  = (const float*)d_in[9];
    const float* w_dense= (const float*)d_in[10];
    float* out = (float*)d_out;

    vin_kernel<<<128, 1024, 0, stream>>>(x, S1, S2, VInum, w0, b0, w_r, w_q,
                                         w_sw, w_sw2, w_dense, out);
}

// Round 6
// 172.753 us; speedup vs baseline: 2.5993x; 1.0226x over previous
//
#include <hip/hip_runtime.h>
#include <math.h>

// VIN forward on MI355X — single fused kernel, 128 WGs x 1024 thr (16 waves,
// 4/SIMD), 4 px/thread. Sizes: N=128, H=W=64, CH_I=2, CH_H=150, CH_Q=10.
//
// R16 -> R17 (K-loop schedule only):
//  R16: TLP 2x -> only -3.5us => not latency-bound; phase-serialized.
//  SQ_LDS_BANK_CONFLICT doubled to 7.85M = ~1750 cyc/CU/iter (~0.73us/iter)
//  — same size as the VALU floor. R16 clustered all 6 v-window reads at the
//  iteration top: post-barrier all 16 waves burst-load, conflict+issue time
//  serializes ahead of an idle VALU (R11 header already recorded "clustered
//  wide loads regress vs sprinkled"). Fix: split the body into 3 stencil-row
//  chunks, each {2 LDS reads -> 60 pk-FMAs}; per-burst queue depth 6 -> 2,
//  loads covered by previous chunk's compute. Accumulation order per (p,ap)
//  chain unchanged (d = 0..8, same operands) -> bit-identical output.
//  acc widens to [4][5] (40 VGPR live); budget ~110 <= 128 (16 waves OK).

typedef float v2f __attribute__((ext_vector_type(2)));

static __device__ __forceinline__ v2f splat2(float s) { v2f r; r.x = s; r.y = s; return r; }
static __device__ __forceinline__ v2f pkfma(v2f w, float v, v2f a) {
#if __has_builtin(__builtin_elementwise_fma)
    return __builtin_elementwise_fma(w, splat2(v), a);
#else
    v2f r; r.x = fmaf(w.x, v, a.x); r.y = fmaf(w.y, v, a.y); return r;
#endif
}
static __device__ __forceinline__ v2f pkmax(v2f a, v2f b) {
#if __has_builtin(__builtin_elementwise_max)
    return __builtin_elementwise_max(a, b);
#else
    v2f r; r.x = fmaxf(a.x, b.x); r.y = fmaxf(a.y, b.y); return r;
#endif
}

#define XROW 69
#define RROW 68                  // rs row stride; addr = row*68 + col + 2
#define VROW2 68                 // vpool row stride; addr = row*68 + col + 2
#define VSTR2 (66 * VROW2)       // 4488 floats per v buffer

__global__ void
__attribute__((amdgpu_flat_work_group_size(1024, 1024)))
__attribute__((amdgpu_waves_per_eu(4, 4)))
vin_kernel(const float* __restrict__ x,
           const int* __restrict__ S1,
           const int* __restrict__ S2,
           const int* __restrict__ VInum,
           const float* __restrict__ w0,
           const float* __restrict__ b0,
           const float* __restrict__ w_r,
           const float* __restrict__ w_q,
           const float* __restrict__ w_sw,
           const float* __restrict__ w_sw2,
           const float* __restrict__ w_dense,
           float* __restrict__ out) {
    const int b = blockIdx.x;
    const int t = threadIdx.x;

    __shared__ float xs0[68 * XROW];     // x ch0, [y+2][x+2], 2-halo of zeros
    __shared__ float xs1[68 * XROW];     // x ch1
    __shared__ float rs[66 * RROW];      // r, pad-2 layout, zero halos
    __shared__ float vpool[2 * VSTR2];   // v double buffer, pad-2 layout
    __shared__ float wtA[1620];          // P chunk partials: 162 entries x 10
    __shared__ float Pp[450];            // P[d][e5x5][ci], zero-init
    __shared__ float Bt[90];             // bias chunk partials
    __shared__ float Bv[9];              // B[d] = w_r[d].b0
    __shared__ float W5c[459];           // 9 classes x (50 weights + bias)
    __shared__ float qsel[10];

    // ---- zero LDS (halos must be 0; Pp must be 0 for invalid combos) ----
    for (int i = t; i < 68 * XROW; i += 1024) { xs0[i] = 0.f; xs1[i] = 0.f; }
    for (int i = t; i < 66 * RROW; i += 1024) rs[i] = 0.f;
    for (int i = t; i < 2 * VSTR2; i += 1024) vpool[i] = 0.f;
    if (t < 450) Pp[t] = 0.f;
    __syncthreads();

    const int row = t >> 4;          // 0..63
    const int cb  = (t & 15) << 2;   // 0,4,...,60  (4 px per thread)

    // ---- stage x (8 contiguous floats = 2x float4 per thread) ----
    {
        const float* xb = x + (size_t)b * 64 * 64 * 2;
        const float4* xp = (const float4*)(xb + (row * 64 + cb) * 2);
        #pragma unroll
        for (int g = 0; g < 2; ++g) {
            float4 v4 = xp[g];
            int px = cb + g * 2;
            xs0[(row + 2) * XROW + px + 2] = v4.x;
            xs1[(row + 2) * XROW + px + 2] = v4.y;
            xs0[(row + 2) * XROW + px + 3] = v4.z;
            xs1[(row + 2) * XROW + px + 3] = v4.w;
        }
    }
    // ---- round A: P chunk partials (1620 items) + bias chunks (90) ----
    for (int idx = t; idx < 1620; idx += 1024) {
        int entry = idx / 10, ch = idx - entry * 10;
        int d = entry / 18, rem = entry % 18;
        int uu = rem >> 1, ci = rem & 1;
        int c0 = ch * 15;
        const float* wr = w_r + d * 150;
        const float* wp = w0 + (uu * 2 + ci) * 150;
        float s = 0.f;
        for (int c = c0; c < c0 + 15; ++c) s += wr[c] * wp[c];
        wtA[idx] = s;
    }
    if (t < 90) {
        int d = t / 10, ch = t - d * 10, c0 = ch * 15;
        float s = 0.f;
        for (int c = c0; c < c0 + 15; ++c) s += w_r[d * 150 + c] * b0[c];
        Bt[t] = s;
    }
    __syncthreads();
    // ---- round B: reduce P entries (162) and B (9) ----
    if (t < 162) {
        float s = 0.f;
        #pragma unroll
        for (int i = 0; i < 10; ++i) s += wtA[t * 10 + i];
        int d = t / 18, rem = t % 18;
        int uu = rem >> 1, ci = rem & 1;
        int dy = d / 3 - 1, dx = d % 3 - 1;
        int uy = uu / 3 - 1, ux = uu % 3 - 1;
        int eidx = (dy + uy + 2) * 5 + (dx + ux + 2);
        Pp[d * 50 + eidx * 2 + ci] = s;
    } else if (t >= 256 && t < 265) {
        int d = t - 256;
        float s = 0.f;
        #pragma unroll
        for (int i = 0; i < 10; ++i) s += Bt[d * 10 + i];
        Bv[d] = s;
    }
    __syncthreads();
    // ---- round C: class subset-sums W5c[9][51] ----
    if (t < 459) {
        int cls = t / 51, j = t - cls * 51;
        int cy = cls / 3, cx = cls % 3;
        float s = 0.f;
        #pragma unroll
        for (int d = 0; d < 9; ++d) {
            int dy = d / 3 - 1, dx = d % 3 - 1;
            bool ok = (cy == 0 || (cy == 1 ? dy >= 0 : dy <= 0)) &&
                      (cx == 0 || (cx == 1 ? dx >= 0 : dx <= 0));
            if (ok) s += (j < 50) ? Pp[d * 50 + j] : Bv[d];
        }
        W5c[t] = s;
    }
    __syncthreads();

    // ---- r everywhere via class-weighted 5x5 stencil (4 px/thread) ----
    {
        int cy = (row == 0) ? 1 : (row == 63) ? 2 : 0;
        #pragma unroll
        for (int p = 0; p < 4; ++p) {
            int xx = cb + p;
            int cx = (xx == 0) ? 1 : (xx == 63) ? 2 : 0;
            const float* Wp = &W5c[(cy * 3 + cx) * 51];
            float acc = Wp[50];
            #pragma unroll
            for (int e = 0; e < 25; ++e) {
                int xi = (row + e / 5) * XROW + (xx + e % 5);
                acc = fmaf(xs0[xi], Wp[e * 2], acc);
                acc = fmaf(xs1[xi], Wp[e * 2 + 1], acc);
            }
            rs[(row + 1) * RROW + xx + 2] = acc;
        }
    }
    __syncthreads();

    const int K = VInum[0];

    // ---- Rsw precompute (packed action-pairs) + first step (w_q) ----
    v2f Rsw2[4][5];
    float vprev[4];
    {
        float rwin[3][6];
        #pragma unroll
        for (int i = 0; i < 3; ++i) {
            const float4* rp = (const float4*)&rs[(row + i) * RROW + cb];
            float4 cA = rp[0], cB = rp[1];
            rwin[i][0] = cA.y; rwin[i][1] = cA.z; rwin[i][2] = cA.w;
            rwin[i][3] = cB.x; rwin[i][4] = cB.y; rwin[i][5] = cB.z;
        }
        float vmax[4];
        #pragma unroll
        for (int a = 0; a < 10; ++a) {
            #pragma unroll
            for (int p = 0; p < 4; ++p) {
                float accR = 0.f, accQ = 0.f;
                #pragma unroll
                for (int d = 0; d < 9; ++d) {
                    float rv = rwin[d / 3][p + d % 3];
                    accR = fmaf(w_sw[d * 20 + a], rv, accR);
                    accQ = fmaf(w_q[d * 20 + a],  rv, accQ);
                }
                if (a & 1) Rsw2[p][a >> 1].y = accR; else Rsw2[p][a >> 1].x = accR;
                vmax[p] = (a == 0) ? accQ : fmaxf(vmax[p], accQ);
            }
        }
        #pragma unroll
        for (int p = 0; p < 4; ++p) {
            vpool[0 * VSTR2 + (row + 1) * VROW2 + cb + p + 2] = vmax[p];
            vprev[p] = vmax[p];
        }
    }
    __syncthreads();

    // ---- K-1 shared-weight VI steps: sprinkled-wide schedule ----
    // 3 chunks per iter, each {<=2 LDS reads -> 60 pk-FMAs}; per-(p,ap)
    // accumulation order d = 0..8 preserved -> bit-identical.
    int cur = 0;
    for (int it = 0; it < K - 1; ++it) {
        const float* vb = &vpool[cur * VSTR2 + row * VROW2 + cb];
        int nxt = cur ^ 1;
        v2f acc[4][5];

        // -- chunk 0: row above (d = 0..2) --
        {
            const float4* r0p = (const float4*)vb;
            float4 a0 = r0p[0], b0v = r0p[1];
            float v0[6];
            v0[0] = a0.y; v0[1] = a0.z; v0[2] = a0.w;
            v0[3] = b0v.x; v0[4] = b0v.y; v0[5] = b0v.z;
            #pragma unroll
            for (int ap = 0; ap < 5; ++ap) {
                #pragma unroll
                for (int dd = 0; dd < 3; ++dd) {
                    v2f w2;
                    w2.x = w_sw[dd * 20 + 10 + 2 * ap];
                    w2.y = w_sw[dd * 20 + 10 + 2 * ap + 1];
                    #pragma unroll
                    for (int p = 0; p < 4; ++p) {
                        float vv = v0[p + dd];
                        acc[p][ap] = (dd == 0) ? pkfma(w2, vv, Rsw2[p][ap])
                                               : pkfma(w2, vv, acc[p][ap]);
                    }
                }
            }
        }
        // -- chunk 1: middle row (d = 3..5); edges from LDS, rest from regs --
        {
            float eL = vb[VROW2 + 1];
            float eR = vb[VROW2 + 6];
            float v1[6];
            v1[0] = eL; v1[5] = eR;
            #pragma unroll
            for (int j = 0; j < 4; ++j) v1[j + 1] = vprev[j];
            #pragma unroll
            for (int ap = 0; ap < 5; ++ap) {
                #pragma unroll
                for (int dd = 0; dd < 3; ++dd) {
                    int d = 3 + dd;
                    v2f w2;
                    w2.x = w_sw[d * 20 + 10 + 2 * ap];
                    w2.y = w_sw[d * 20 + 10 + 2 * ap + 1];
                    #pragma unroll
                    for (int p = 0; p < 4; ++p)
                        acc[p][ap] = pkfma(w2, v1[p + dd], acc[p][ap]);
                }
            }
        }
        // -- chunk 2: row below (d = 6..8) --
        {
            const float4* r2p = (const float4*)(vb + 2 * VROW2);
            float4 a2 = r2p[0], b2v = r2p[1];
            float v2a[6];
            v2a[0] = a2.y; v2a[1] = a2.z; v2a[2] = a2.w;
            v2a[3] = b2v.x; v2a[4] = b2v.y; v2a[5] = b2v.z;
            #pragma unroll
            for (int ap = 0; ap < 5; ++ap) {
                #pragma unroll
                for (int dd = 0; dd < 3; ++dd) {
                    int d = 6 + dd;
                    v2f w2;
                    w2.x = w_sw[d * 20 + 10 + 2 * ap];
                    w2.y = w_sw[d * 20 + 10 + 2 * ap + 1];
                    #pragma unroll
                    for (int p = 0; p < 4; ++p)
                        acc[p][ap] = pkfma(w2, v2a[p + dd], acc[p][ap]);
                }
            }
        }
        // -- max over actions (same order as before), publish, carry --
        float vnew[4];
        #pragma unroll
        for (int p = 0; p < 4; ++p) {
            v2f m2 = acc[p][0];
            #pragma unroll
            for (int ap = 1; ap < 5; ++ap) m2 = pkmax(m2, acc[p][ap]);
            vnew[p] = fmaxf(m2.x, m2.y);
        }
        float* vw = &vpool[nxt * VSTR2 + (row + 1) * VROW2 + cb + 2];
        *(float2*)&vw[0] = make_float2(vnew[0], vnew[1]);   // ds_write_b64
        *(float2*)&vw[2] = make_float2(vnew[2], vnew[3]);   // ds_write_b64
        #pragma unroll
        for (int p = 0; p < 4; ++p) vprev[p] = vnew[p];

        cur = nxt;
        __syncthreads();
    }

    // ---- final step with w_sw2: q -> global, gather (S1,S2) ----
    const int s1 = S1[b], s2 = S2[b];
    {
        float rwin[3][6], vwin[3][6];
        #pragma unroll
        for (int i = 0; i < 3; ++i) {
            const float4* rp = (const float4*)&rs[(row + i) * RROW + cb];
            float4 cA = rp[0], cB = rp[1];
            rwin[i][0] = cA.y; rwin[i][1] = cA.z; rwin[i][2] = cA.w;
            rwin[i][3] = cB.x; rwin[i][4] = cB.y; rwin[i][5] = cB.z;
        }
        const float* vb = &vpool[cur * VSTR2 + row * VROW2 + cb];
        {
            const float4* r0p = (const float4*)vb;
            const float4* r2p = (const float4*)(vb + 2 * VROW2);
            float4 a0 = r0p[0], b0v = r0p[1];
            float4 a2 = r2p[0], b2v = r2p[1];
            vwin[0][0] = a0.y; vwin[0][1] = a0.z; vwin[0][2] = a0.w;
            vwin[0][3] = b0v.x; vwin[0][4] = b0v.y; vwin[0][5] = b0v.z;
            vwin[2][0] = a2.y; vwin[2][1] = a2.z; vwin[2][2] = a2.w;
            vwin[2][3] = b2v.x; vwin[2][4] = b2v.y; vwin[2][5] = b2v.z;
            vwin[1][0] = vb[VROW2 + 1]; vwin[1][5] = vb[VROW2 + 6];
            #pragma unroll
            for (int j = 0; j < 4; ++j) vwin[1][j + 1] = vprev[j];
        }
        float qv[4][10];
        #pragma unroll
        for (int a = 0; a < 10; ++a) {
            #pragma unroll
            for (int p = 0; p < 4; ++p) {
                float acc = 0.f;
                #pragma unroll
                for (int d = 0; d < 9; ++d) {
                    acc = fmaf(w_sw2[d * 20 + a],      rwin[d / 3][p + d % 3], acc);
                    acc = fmaf(w_sw2[d * 20 + 10 + a], vwin[d / 3][p + d % 3], acc);
                }
                qv[p][a] = acc;
            }
        }
        // store q: 40 contiguous floats (4 px x 10 actions), 16B-aligned
        {
            float4* qp4 = (float4*)(out + 2048 + ((size_t)((b * 64 + row) * 64 + cb)) * 10);
            #pragma unroll
            for (int g = 0; g < 10; ++g)
                qp4[g] = make_float4(qv[(g * 4) / 10][(g * 4) % 10],
                                     qv[(g * 4 + 1) / 10][(g * 4 + 1) % 10],
                                     qv[(g * 4 + 2) / 10][(g * 4 + 2) % 10],
                                     qv[(g * 4 + 3) / 10][(g * 4 + 3) % 10]);
        }
        if (row == s1) {
            #pragma unroll
            for (int p = 0; p < 4; ++p)
                if (s2 == cb + p) {
                    #pragma unroll
                    for (int a = 0; a < 10; ++a) qsel[a] = qv[p][a];
                }
        }
    }
    __syncthreads();

    // ---- dense + softmax (thread 0), q_out (threads 0..9) ----
    if (t == 0) {
        float logits[8];
        float m = -1e30f;
        #pragma unroll
        for (int j = 0; j < 8; ++j) {
            float s = 0.f;
            #pragma unroll
            for (int a = 0; a < 10; ++a) s += qsel[a] * w_dense[a * 8 + j];
            logits[j] = s;
            m = fmaxf(m, s);
        }
        float sum = 0.f;
        float e[8];
        #pragma unroll
        for (int j = 0; j < 8; ++j) { e[j] = expf(logits[j] - m); sum += e[j]; }
        float inv = 1.f / sum;
        #pragma unroll
        for (int j = 0; j < 8; ++j) {
            out[b * 8 + j] = logits[j];
            out[1024 + b * 8 + j] = e[j] * inv;
        }
    }
    if (t < 10) out[5244928 + b * 10 + t] = qsel[t];
}

extern "C" void kernel_launch(void* const* d_in, const int* in_sizes, int n_in,
                              void* d_out, int out_size, void* d_ws, size_t ws_size,
                              hipStream_t stream) {
    const float* x      = (const float*)d_in[0];
    const int*   S1     = (const int*)d_in[1];
    const int*   S2     = (const int*)d_in[2];
    const int*   VInum  = (const int*)d_in[3];
    const float* w0     = (const float*)d_in[4];
    const float* b0     = (const float*)d_in[5];
    const float* w_r    = (const float*)d_in[6];
    const float* w_q    = (const float*)d_in[7];
    const float* w_sw   = (const float*)d_in[8];
    const float* w_sw2  = (const float*)d_in[9];
    const float* w_dense= (const float*)d_in[10];
    float* out = (float*)d_out;

    vin_kernel<<<128, 1024, 0, stream>>>(x, S1, S2, VInum, w0, b0, w_r, w_q,
                                         w_sw, w_sw2, w_dense, out);
}